// Round 7
// baseline (370.309 us; speedup 1.0000x reference)
//
#include <hip/hip_runtime.h>

#define N_NODES 100000
#define IN_C    128
#define OUT_C   200
#define NT_TILES 13            // ceil(200/16)
#define KT_TILES 4             // 128/32

// ---- bucket partition params ----------------------------------------------
#define PSHIFT  8
#define NPB     256                        // nodes per bucket = 1<<PSHIFT
#define NB      391                        // ceil(100000/256)
#define NB_POW2 512
#define BCAP    5120                       // per-bucket capacity (mean 4092, +16 sigma)
#define PART_CH 4096                       // edges per partition block (391 blocks)
#define SEQ_P   16                         // PART_CH/256 edges per thread
#define SEQ_B   20                         // ceil(BCAP/256) entries per thread

typedef __bf16 bf16_t;
typedef bf16_t bf16x8 __attribute__((ext_vector_type(8)));
typedef float  f32x4  __attribute__((ext_vector_type(4)));
typedef unsigned int u32x2 __attribute__((ext_vector_type(2)));

// ---- bf16 bit helpers (RNE) -----------------------------------------------
__device__ __forceinline__ unsigned int bf16_bits(float f) {
    unsigned int u = __builtin_bit_cast(unsigned int, f);
    return (u + 0x7FFFu + ((u >> 16) & 1u)) >> 16;
}
__device__ __forceinline__ float bf16_lo(unsigned int p) {
    return __builtin_bit_cast(float, p << 16);
}
__device__ __forceinline__ float bf16_hi(unsigned int p) {
    return __builtin_bit_cast(float, p & 0xFFFF0000u);
}

// ---------------------------------------------------------------------------
// 1. partition edges into NB dst-buckets, LDS-staged so global writes are
//    coalesced runs. SINGLE edge pass: the histogram atomicAdd's return value
//    is the in-block sequence number.
// ---------------------------------------------------------------------------
__global__ __launch_bounds__(256) void partition_kernel(
        const int* __restrict__ row, const int* __restrict__ col, int E,
        int* __restrict__ gcount, unsigned int* __restrict__ gbuf) {
    __shared__ int hist[NB];
    __shared__ int base[NB];
    __shared__ int lofs[NB];
    __shared__ int pscan[256];
    __shared__ unsigned int stage[PART_CH];
    __shared__ unsigned short sb[PART_CH];
    const int tid = threadIdx.x;
    const int chunk = blockIdx.x * PART_CH;
    int cend = E - chunk; if (cend > PART_CH) cend = PART_CH;

    for (int i = tid; i < NB; i += 256) hist[i] = 0;
    __syncthreads();

    // single pass: histogram + remember (payload, bucket, seq) in registers
    unsigned int   pay[SEQ_P];
    unsigned short eb[SEQ_P];
    unsigned short sq[SEQ_P];
    #pragma unroll
    for (int k = 0; k < SEQ_P; k++) {
        int i = tid + k * 256;
        eb[k] = 0xFFFFu;
        if (i < cend) {
            int c = __builtin_nontemporal_load(col + chunk + i);
            int r = __builtin_nontemporal_load(row + chunk + i);
            int b = (c >> PSHIFT) & (NB_POW2 - 1);
            if (b >= NB) b = NB - 1;
            pay[k] = (unsigned int)((c & (NPB - 1)) | (r << PSHIFT));
            eb[k]  = (unsigned short)b;
            sq[k]  = (unsigned short)atomicAdd(&hist[b], 1);
        }
    }
    __syncthreads();

    // reserve global space per bucket (disjoint across blocks)
    for (int i = tid; i < NB; i += 256)
        base[i] = atomicAdd(&gcount[i], hist[i]);

    // exclusive scan of hist -> lofs (pair-per-thread Hillis-Steele)
    int v0 = (2 * tid     < NB) ? hist[2 * tid]     : 0;
    int v1 = (2 * tid + 1 < NB) ? hist[2 * tid + 1] : 0;
    int s = v0 + v1;
    pscan[tid] = s;
    __syncthreads();
    for (int off = 1; off < 256; off <<= 1) {
        int u = (tid >= off) ? pscan[tid - off] : 0;
        __syncthreads();
        pscan[tid] += u;
        __syncthreads();
    }
    int ep = pscan[tid] - s;                 // exclusive over pairs
    if (2 * tid     < NB) lofs[2 * tid]     = ep;
    if (2 * tid + 1 < NB) lofs[2 * tid + 1] = ep + v0;
    __syncthreads();

    // place staged entries (no atomics: p = lofs[bucket] + seq)
    #pragma unroll
    for (int k = 0; k < SEQ_P; k++) {
        if (eb[k] != 0xFFFFu) {
            int p = lofs[eb[k]] + sq[k];
            stage[p] = pay[k];
            sb[p] = eb[k];
        }
    }
    __syncthreads();

    // flush — consecutive i within a bucket run -> contiguous global
    for (int i = tid; i < cend; i += 256) {
        int b = sb[i];
        int p = base[b] + (i - lofs[b]);
        if (p < BCAP) gbuf[(size_t)b * BCAP + p] = stage[i];
    }
}

// exclusive scan of NB bucket counts -> per-bucket CSR base
__global__ void bucket_scan_kernel(const int* __restrict__ gcount, int* __restrict__ gbase) {
    __shared__ int pscan[256];
    int tid = threadIdx.x;
    int v0 = (2 * tid     < NB) ? gcount[2 * tid]     : 0;
    int v1 = (2 * tid + 1 < NB) ? gcount[2 * tid + 1] : 0;
    if (v0 > BCAP) v0 = BCAP;
    if (v1 > BCAP) v1 = BCAP;
    int s = v0 + v1;
    pscan[tid] = s;
    __syncthreads();
    for (int off = 1; off < 256; off <<= 1) {
        int u = (tid >= off) ? pscan[tid - off] : 0;
        __syncthreads();
        pscan[tid] += u;
        __syncthreads();
    }
    int ep = pscan[tid] - s;
    if (2 * tid     < NB) gbase[2 * tid]     = ep;
    if (2 * tid + 1 < NB) gbase[2 * tid + 1] = ep + v0;
}

// ---------------------------------------------------------------------------
// 2. per-bucket CSR build: deg + offsets + dinv + fill, SINGLE entry pass
//    (count-atomic returns seq). Scatter confined to one block's region.
// ---------------------------------------------------------------------------
__global__ __launch_bounds__(256) void build_kernel(
        const unsigned int* __restrict__ gbuf, const int* __restrict__ gcount,
        const int* __restrict__ gbase, int* __restrict__ deg,
        int* __restrict__ offsets, float* __restrict__ dinv,
        int* __restrict__ csr_src, int n) {
    __shared__ int cnt[NPB];
    __shared__ int cur[NPB];
    __shared__ int pscan[256];
    const int b = blockIdx.x;
    const int tid = threadIdx.x;
    int total = gcount[b]; if (total > BCAP) total = BCAP;
    const int cbase = gbase[b];
    const unsigned int* bp = gbuf + (size_t)b * BCAP;

    cnt[tid] = 0;
    __syncthreads();

    unsigned int   ee[SEQ_B];
    unsigned short sq[SEQ_B];
    #pragma unroll
    for (int k = 0; k < SEQ_B; k++) {
        int i = tid + k * 256;
        ee[k] = 0xFFFFFFFFu;
        if (i < total) {
            unsigned int e = __builtin_nontemporal_load(bp + i);
            ee[k] = e;
            sq[k] = (unsigned short)atomicAdd(&cnt[e & (NPB - 1)], 1);
        }
    }
    __syncthreads();

    int c = cnt[tid];
    pscan[tid] = c;
    __syncthreads();
    for (int off = 1; off < 256; off <<= 1) {
        int u = (tid >= off) ? pscan[tid - off] : 0;
        __syncthreads();
        pscan[tid] += u;
        __syncthreads();
    }
    int excl = pscan[tid] - c;
    cur[tid] = excl;
    int v = b * NPB + tid;
    if (v < n) {
        deg[v] = c;
        offsets[v] = cbase + excl;
        dinv[v] = rsqrtf((float)(c + 1));   // +1 self-loop
    }
    __syncthreads();

    #pragma unroll
    for (int k = 0; k < SEQ_B; k++) {
        if (ee[k] != 0xFFFFFFFFu) {
            int p = cur[ee[k] & (NPB - 1)] + (int)sq[k];
            csr_src[cbase + p] = (int)(ee[k] >> PSHIFT);
        }
    }
}

// ---------------------------------------------------------------------------
// 3. xs = dinv[v] * x[v]  ->  packed bf16x2 (f32x4 NT in, uint2 out)
// ---------------------------------------------------------------------------
__global__ void convert_xs_kernel(const float* __restrict__ x, const float* __restrict__ dinv,
                                  uint2* __restrict__ xs4, int n) {
    int id = blockIdx.x * blockDim.x + threadIdx.x;   // n*32 total
    if (id >= n * 32) return;
    int v = id >> 5;
    float dv = dinv[v];
    f32x4 f = __builtin_nontemporal_load((const f32x4*)x + id);
    uint2 o;
    o.x = bf16_bits(f.x * dv) | (bf16_bits(f.y * dv) << 16);
    o.y = bf16_bits(f.z * dv) | (bf16_bits(f.w * dv) << 16);
    xs4[id] = o;
}

// ---------------------------------------------------------------------------
// 4. gather: agg[v] = dv * ( xs[v] + sum_{u->v} xs[u] )
//    One wave per node. BATCHED: per 32-edge round, each half (32 lanes)
//    issues all <=16 index loads (independent, one 128B line), then all <=16
//    row loads (independent, 16 uint2 in flight) -> ~2 latency rounds per
//    node instead of 4-6 (mean deg=16 => one round covers ~97% of nodes).
// ---------------------------------------------------------------------------
__global__ __launch_bounds__(256) void gather_kernel(
        const uint2* __restrict__ xs4, const float* __restrict__ dinv,
        const int* __restrict__ offsets, const int* __restrict__ deg,
        const int* __restrict__ csr_src, uint2* __restrict__ agg4, int n) {
    int wave = threadIdx.x >> 6;
    int lane = threadIdx.x & 63;
    int half = lane >> 5;          // which edge of each pair
    int hl   = lane & 31;          // channel-pair index (4 channels per lane)
    int v = blockIdx.x * 4 + wave;
    if (v >= n) return;
    float dv = dinv[v];
    int start = offsets[v];
    int cnt = deg[v];
    float ax = 0.f, ay = 0.f, az = 0.f, aw = 0.f;

    const int* cp = csr_src + start;
    for (int base = 0; base < cnt; base += 32) {
        // phase 1: all index loads (half-uniform addresses, one line)
        int idx[16];
        #pragma unroll
        for (int j = 0; j < 16; j++) {
            int e = base + 2 * j + half;
            idx[j] = (e < cnt) ? __builtin_nontemporal_load(cp + e) : -1;
        }
        // phase 2: all row loads in flight at once
        uint2 t[16];
        #pragma unroll
        for (int j = 0; j < 16; j++) {
            if (idx[j] >= 0) t[j] = xs4[(size_t)idx[j] * 32 + hl];
            else             t[j] = (uint2){0u, 0u};
        }
        // phase 3: accumulate
        #pragma unroll
        for (int j = 0; j < 16; j++) {
            ax += bf16_lo(t[j].x); ay += bf16_hi(t[j].x);
            az += bf16_lo(t[j].y); aw += bf16_hi(t[j].y);
        }
    }
    // combine the two halves (each edge was processed by exactly one half)
    ax += __shfl_xor(ax, 32, 64);
    ay += __shfl_xor(ay, 32, 64);
    az += __shfl_xor(az, 32, 64);
    aw += __shfl_xor(aw, 32, 64);
    // self-loop (added once post-combine; both halves compute, half 0 writes)
    uint2 s = xs4[(size_t)v * 32 + hl];
    ax += bf16_lo(s.x); ay += bf16_hi(s.x);
    az += bf16_lo(s.y); aw += bf16_hi(s.y);
    if (half == 0) {
        uint2 o;
        o.x = bf16_bits(ax * dv) | (bf16_bits(ay * dv) << 16);
        o.y = bf16_bits(az * dv) | (bf16_bits(aw * dv) << 16);
        agg4[(size_t)v * 32 + hl] = o;
    }
}

// ---------------------------------------------------------------------------
// 5. pack W1+W2 -> bf16 MFMA B-fragment order, nt-major: [nt][h][kt][lane][8]
// ---------------------------------------------------------------------------
__global__ void pack_w_kernel(const float* __restrict__ W1, const float* __restrict__ W2,
                              unsigned short* __restrict__ out) {
    int tid = blockIdx.x * blockDim.x + threadIdx.x;   // 2*KT*NT*64 = 6656
    if (tid >= 2 * KT_TILES * NT_TILES * 64) return;
    int lane = tid & 63;
    int nt = (tid >> 6) % NT_TILES;
    int kt = (tid / (64 * NT_TILES)) % KT_TILES;
    int h  = tid / (64 * NT_TILES * KT_TILES);
    const float* W = h ? W2 : W1;
    int q = lane >> 4, r = lane & 15;
    int nn = nt * 16 + r;
    size_t dst = ((size_t)((nt * 2 + h) * KT_TILES + kt)) * 512 + (size_t)lane * 8;
    for (int j = 0; j < 8; j++) {
        int k = kt * 32 + q * 8 + j;
        float val = (nn < OUT_C) ? W[(size_t)k * OUT_C + nn] : 0.f;
        out[dst + j] = (unsigned short)bf16_bits(val);
    }
}

// ---------------------------------------------------------------------------
// 6. fused 2-head MFMA GEMM with per-nt LDS staging of B (double-buffered,
//    register prefetch, one barrier per nt). Epilogue: biases hoisted; stores
//    row-major runs, non-temporal (outputs never re-read -> keep L2 clean).
// ---------------------------------------------------------------------------
__global__ __launch_bounds__(256) void gemm_mfma_kernel(
        const unsigned short* __restrict__ agg,   // [M][128] bf16
        const unsigned short* __restrict__ Wpk,   // [NT][2][KT][64][8] bf16
        const float* __restrict__ b1, const float* __restrict__ b2,
        float* __restrict__ mu, float* __restrict__ ls, int M) {
    __shared__ uint4 Bs[2][512];                  // 2 x 8KB nt-slices
    int tid  = threadIdx.x;
    int wave = tid >> 6;
    int lane = tid & 63;
    int row0 = blockIdx.x * 64 + wave * 16;
    int q = lane >> 4, r = lane & 15;

    // A fragments: A[m = lane&15][k = q*8 + j], one per kt
    int arow = row0 + r; if (arow > M - 1) arow = M - 1;
    const unsigned short* ap = agg + (size_t)arow * IN_C + q * 8;
    bf16x8 afrag[KT_TILES];
    #pragma unroll
    for (int kt = 0; kt < KT_TILES; kt++) {
        uint4 u = *(const uint4*)(ap + kt * 32);
        afrag[kt] = __builtin_bit_cast(bf16x8, u);
    }

    f32x4 acc[2][NT_TILES];
    #pragma unroll
    for (int h = 0; h < 2; h++)
        #pragma unroll
        for (int nt = 0; nt < NT_TILES; nt++)
            acc[h][nt] = (f32x4){0.f, 0.f, 0.f, 0.f};

    const uint4* wsrc = (const uint4*)Wpk;
    uint4 pre0 = wsrc[tid];
    uint4 pre1 = wsrc[tid + 256];

    for (int nt = 0; nt < NT_TILES; nt++) {
        int buf = nt & 1;
        Bs[buf][tid]       = pre0;
        Bs[buf][tid + 256] = pre1;
        __syncthreads();
        if (nt + 1 < NT_TILES) {
            pre0 = wsrc[(nt + 1) * 512 + tid];
            pre1 = wsrc[(nt + 1) * 512 + tid + 256];
        }
        #pragma unroll
        for (int h = 0; h < 2; h++) {
            f32x4 c = acc[h][nt];
            #pragma unroll
            for (int kt = 0; kt < KT_TILES; kt++) {
                uint4 u = Bs[buf][(h * KT_TILES + kt) * 64 + lane];
                bf16x8 bfrag = __builtin_bit_cast(bf16x8, u);
                c = __builtin_amdgcn_mfma_f32_16x16x32_bf16(afrag[kt], bfrag, c, 0, 0, 0);
            }
            acc[h][nt] = c;
        }
        // buffer written next at nt+2; all waves passed the nt+1 barrier by then
    }

    // epilogue: C/D layout col = lane&15, row = q*4 + reg
    float bv1r[NT_TILES], bv2r[NT_TILES];
    #pragma unroll
    for (int nt = 0; nt < NT_TILES; nt++) {
        int colx = nt * 16 + r;
        bool cok = colx < OUT_C;
        bv1r[nt] = cok ? b1[colx] : 0.f;
        bv2r[nt] = cok ? b2[colx] : 0.f;
    }
    #pragma unroll
    for (int reg = 0; reg < 4; reg++) {
        int gr = row0 + q * 4 + reg;
        if (gr < M) {
            float* mrow = mu + (size_t)gr * OUT_C;
            #pragma unroll
            for (int nt = 0; nt < NT_TILES; nt++) {
                int colx = nt * 16 + r;
                if (colx < OUT_C)
                    __builtin_nontemporal_store(acc[0][nt][reg] + bv1r[nt], mrow + colx);
            }
            float* lrow = ls + (size_t)gr * OUT_C;
            #pragma unroll
            for (int nt = 0; nt < NT_TILES; nt++) {
                int colx = nt * 16 + r;
                if (colx < OUT_C)
                    __builtin_nontemporal_store(acc[1][nt][reg] + bv2r[nt], lrow + colx);
            }
        }
    }
}

// ---------------------------------------------------------------------------
extern "C" void kernel_launch(void* const* d_in, const int* in_sizes, int n_in,
                              void* d_out, int out_size, void* d_ws, size_t ws_size,
                              hipStream_t stream) {
    const float* x  = (const float*)d_in[0];
    const int*   ei = (const int*)d_in[1];
    const float* W1 = (const float*)d_in[2];
    const float* b1 = (const float*)d_in[3];
    const float* W2 = (const float*)d_in[4];
    const float* b2 = (const float*)d_in[5];

    const int n = in_sizes[0] / IN_C;      // 100000
    const int E = in_sizes[1] / 2;         // 1600000
    const int* row = ei;                   // src
    const int* col = ei + E;               // dst

    float* mu = (float*)d_out;
    float* ls = (float*)d_out + (size_t)n * OUT_C;

    // workspace layout (byte offsets, 16B aligned)
    char* ws = (char*)d_ws;
    int*            deg     = (int*)           (ws + 0);
    float*          dinv    = (float*)         (ws + 524288);
    int*            offsets = (int*)           (ws + 1048576);
    int*            gcount  = (int*)           (ws + 1572864);          // NB ints
    int*            gbase   = (int*)           (ws + 1576960);          // NB ints
    int*            csr_src = (int*)           (ws + 2162688);          // E ints
    unsigned int*   xs2     = (unsigned int*)  (ws + 8562688);          // n*64 uints
    unsigned int*   gbuf    = (unsigned int*)  (ws + 34162688);         // NB*BCAP uints
    unsigned int*   agg2    = (unsigned int*)  (ws + 42170368);         // n*64 uints
    unsigned short* Wpk     = (unsigned short*)(ws + 67770368);         // 2*3328*8 bf16

    (void)hipMemsetAsync(gcount, 0, NB * sizeof(int), stream);

    pack_w_kernel<<<(2 * KT_TILES * NT_TILES * 64 + 255) / 256, 256, 0, stream>>>(W1, W2, Wpk);

    partition_kernel<<<(E + PART_CH - 1) / PART_CH, 256, 0, stream>>>(row, col, E, gcount, gbuf);
    bucket_scan_kernel<<<1, 256, 0, stream>>>(gcount, gbase);
    build_kernel<<<NB, 256, 0, stream>>>(gbuf, gcount, gbase, deg, offsets, dinv, csr_src, n);

    convert_xs_kernel<<<(n * 32 + 255) / 256, 256, 0, stream>>>(
        x, dinv, (uint2*)xs2, n);

    gather_kernel<<<(n + 3) / 4, 256, 0, stream>>>(
        (const uint2*)xs2, dinv, offsets, deg, csr_src, (uint2*)agg2, n);

    gemm_mfma_kernel<<<(n + 63) / 64, 256, 0, stream>>>(
        (const unsigned short*)agg2, Wpk, b1, b2, mu, ls, n);
}

// Round 8
// 364.542 us; speedup vs baseline: 1.0158x; 1.0158x over previous
//
#include <hip/hip_runtime.h>

#define N_NODES 100000
#define IN_C    128
#define OUT_C   200
#define NT_TILES 13            // ceil(200/16)
#define KT_TILES 4             // 128/32

// ---- bucket partition params ----------------------------------------------
#define PSHIFT  8
#define NPB     256                        // nodes per bucket = 1<<PSHIFT
#define NB      391                        // ceil(100000/256)
#define NB_POW2 512
#define BCAP    5120                       // per-bucket capacity (mean 4092, +16 sigma)
#define PART_CH 4096                       // edges per partition block (391 blocks)
#define SEQ_P   16                         // PART_CH/256 edges per thread
#define SEQ_B   20                         // ceil(BCAP/256) entries per thread

typedef __bf16 bf16_t;
typedef bf16_t bf16x8 __attribute__((ext_vector_type(8)));
typedef float  f32x4  __attribute__((ext_vector_type(4)));

// ---- bf16 bit helpers (RNE) -----------------------------------------------
__device__ __forceinline__ unsigned int bf16_bits(float f) {
    unsigned int u = __builtin_bit_cast(unsigned int, f);
    return (u + 0x7FFFu + ((u >> 16) & 1u)) >> 16;
}
__device__ __forceinline__ float bf16_lo(unsigned int p) {
    return __builtin_bit_cast(float, p << 16);
}
__device__ __forceinline__ float bf16_hi(unsigned int p) {
    return __builtin_bit_cast(float, p & 0xFFFF0000u);
}

// ---------------------------------------------------------------------------
// 1. partition edges into NB dst-buckets, LDS-staged so global writes are
//    coalesced runs. SINGLE edge pass: the histogram atomicAdd's return value
//    is the in-block sequence number.
// ---------------------------------------------------------------------------
__global__ __launch_bounds__(256) void partition_kernel(
        const int* __restrict__ row, const int* __restrict__ col, int E,
        int* __restrict__ gcount, unsigned int* __restrict__ gbuf) {
    __shared__ int hist[NB];
    __shared__ int base[NB];
    __shared__ int lofs[NB];
    __shared__ int pscan[256];
    __shared__ unsigned int stage[PART_CH];
    __shared__ unsigned short sb[PART_CH];
    const int tid = threadIdx.x;
    const int chunk = blockIdx.x * PART_CH;
    int cend = E - chunk; if (cend > PART_CH) cend = PART_CH;

    for (int i = tid; i < NB; i += 256) hist[i] = 0;
    __syncthreads();

    // single pass: histogram + remember (payload, bucket, seq) in registers
    unsigned int   pay[SEQ_P];
    unsigned short eb[SEQ_P];
    unsigned short sq[SEQ_P];
    #pragma unroll
    for (int k = 0; k < SEQ_P; k++) {
        int i = tid + k * 256;
        eb[k] = 0xFFFFu;
        if (i < cend) {
            int c = __builtin_nontemporal_load(col + chunk + i);
            int r = __builtin_nontemporal_load(row + chunk + i);
            int b = (c >> PSHIFT) & (NB_POW2 - 1);
            if (b >= NB) b = NB - 1;
            pay[k] = (unsigned int)((c & (NPB - 1)) | (r << PSHIFT));
            eb[k]  = (unsigned short)b;
            sq[k]  = (unsigned short)atomicAdd(&hist[b], 1);
        }
    }
    __syncthreads();

    // reserve global space per bucket (disjoint across blocks)
    for (int i = tid; i < NB; i += 256)
        base[i] = atomicAdd(&gcount[i], hist[i]);

    // exclusive scan of hist -> lofs (pair-per-thread Hillis-Steele)
    int v0 = (2 * tid     < NB) ? hist[2 * tid]     : 0;
    int v1 = (2 * tid + 1 < NB) ? hist[2 * tid + 1] : 0;
    int s = v0 + v1;
    pscan[tid] = s;
    __syncthreads();
    for (int off = 1; off < 256; off <<= 1) {
        int u = (tid >= off) ? pscan[tid - off] : 0;
        __syncthreads();
        pscan[tid] += u;
        __syncthreads();
    }
    int ep = pscan[tid] - s;                 // exclusive over pairs
    if (2 * tid     < NB) lofs[2 * tid]     = ep;
    if (2 * tid + 1 < NB) lofs[2 * tid + 1] = ep + v0;
    __syncthreads();

    // place staged entries (no atomics: p = lofs[bucket] + seq)
    #pragma unroll
    for (int k = 0; k < SEQ_P; k++) {
        if (eb[k] != 0xFFFFu) {
            int p = lofs[eb[k]] + sq[k];
            stage[p] = pay[k];
            sb[p] = eb[k];
        }
    }
    __syncthreads();

    // flush — consecutive i within a bucket run -> contiguous global
    for (int i = tid; i < cend; i += 256) {
        int b = sb[i];
        int p = base[b] + (i - lofs[b]);
        if (p < BCAP) gbuf[(size_t)b * BCAP + p] = stage[i];
    }
}

// ---------------------------------------------------------------------------
// 2. per-bucket CSR build + in-block bucket prefix (replaces bucket_scan) +
//    fused convert (xs = dinv*x -> bf16x2) for this bucket's 256 nodes.
// ---------------------------------------------------------------------------
__global__ __launch_bounds__(256) void build_kernel(
        const unsigned int* __restrict__ gbuf, const int* __restrict__ gcount,
        const float* __restrict__ x,
        int* __restrict__ deg, int* __restrict__ offsets, float* __restrict__ dinv,
        int* __restrict__ csr_src, uint2* __restrict__ xs4, int n) {
    __shared__ int cnt[NPB];
    __shared__ int cur[NPB];
    __shared__ int pscan[256];
    __shared__ int gb[512];
    const int b = blockIdx.x;
    const int tid = threadIdx.x;

    // ---- in-block exclusive prefix over clamped bucket counts ----
    int g0 = (2 * tid     < NB) ? gcount[2 * tid]     : 0;
    int g1 = (2 * tid + 1 < NB) ? gcount[2 * tid + 1] : 0;
    if (g0 > BCAP) g0 = BCAP;
    if (g1 > BCAP) g1 = BCAP;
    int gs = g0 + g1;
    pscan[tid] = gs;
    cnt[tid] = 0;
    __syncthreads();
    for (int off = 1; off < 256; off <<= 1) {
        int u = (tid >= off) ? pscan[tid - off] : 0;
        __syncthreads();
        pscan[tid] += u;
        __syncthreads();
    }
    int gep = pscan[tid] - gs;
    gb[2 * tid]     = gep;
    gb[2 * tid + 1] = gep + g0;
    __syncthreads();

    const int cbase = gb[b];
    int total = gcount[b]; if (total > BCAP) total = BCAP;
    const unsigned int* bp = gbuf + (size_t)b * BCAP;

    // ---- single entry pass: count-atomic returns sequence number ----
    unsigned int   ee[SEQ_B];
    unsigned short sq[SEQ_B];
    #pragma unroll
    for (int k = 0; k < SEQ_B; k++) {
        int i = tid + k * 256;
        ee[k] = 0xFFFFFFFFu;
        if (i < total) {
            unsigned int e = __builtin_nontemporal_load(bp + i);
            ee[k] = e;
            sq[k] = (unsigned short)atomicAdd(&cnt[e & (NPB - 1)], 1);
        }
    }
    __syncthreads();

    // ---- per-node exclusive scan -> offsets/deg/dinv ----
    int c = cnt[tid];
    pscan[tid] = c;
    __syncthreads();
    for (int off = 1; off < 256; off <<= 1) {
        int u = (tid >= off) ? pscan[tid - off] : 0;
        __syncthreads();
        pscan[tid] += u;
        __syncthreads();
    }
    int excl = pscan[tid] - c;
    cur[tid] = excl;
    int v = b * NPB + tid;
    if (v < n) {
        deg[v] = c;
        offsets[v] = cbase + excl;
        dinv[v] = rsqrtf((float)(c + 1));   // +1 self-loop
    }
    __syncthreads();

    // ---- CSR fill (block-local region -> full L2 lines) ----
    #pragma unroll
    for (int k = 0; k < SEQ_B; k++) {
        if (ee[k] != 0xFFFFFFFFu) {
            int p = cur[ee[k] & (NPB - 1)] + (int)sq[k];
            csr_src[cbase + p] = (int)(ee[k] >> PSHIFT);
        }
    }

    // ---- fused convert: this bucket's 256 x-rows -> xs4 (coalesced) ----
    // half-wave (32 lanes) handles one node's 32 f32x4 chunks per iteration
    int wv = tid >> 6, ln = tid & 63;
    int hlf = ln >> 5, hl2 = ln & 31;
    for (int m = 0; m < 64; m += 2) {
        int local = wv * 64 + m + hlf;
        int nv = b * NPB + local;
        if (nv < n) {
            float dv = rsqrtf((float)(cnt[local] + 1));
            f32x4 f = __builtin_nontemporal_load((const f32x4*)x + (size_t)nv * 32 + hl2);
            uint2 o;
            o.x = bf16_bits(f.x * dv) | (bf16_bits(f.y * dv) << 16);
            o.y = bf16_bits(f.z * dv) | (bf16_bits(f.w * dv) << 16);
            xs4[(size_t)nv * 32 + hl2] = o;
        }
    }
}

// ---------------------------------------------------------------------------
// 3. gather: agg[v] = dv * ( xs[v] + sum_{u->v} xs[u] )
//    one wave per node, 2 edges per iteration via uint2 (8B/lane); full
//    16/8/4/2/1 ladder (R5's best-measured config; R7 batching regressed).
// ---------------------------------------------------------------------------
__global__ __launch_bounds__(256) void gather_kernel(
        const uint2* __restrict__ xs4, const float* __restrict__ dinv,
        const int* __restrict__ offsets, const int* __restrict__ deg,
        const int* __restrict__ csr_src, uint2* __restrict__ agg4, int n) {
    int wave = threadIdx.x >> 6;
    int lane = threadIdx.x & 63;
    int half = lane >> 5;          // which edge of the pair
    int hl   = lane & 31;          // channel-pair index (4 channels per lane)
    int v = blockIdx.x * 4 + wave;
    if (v >= n) return;
    float dv = dinv[v];
    int start = offsets[v];
    int cnt = deg[v];
    float ax = 0.f, ay = 0.f, az = 0.f, aw = 0.f;

    const int* cp = csr_src + start;
    int i = 0;
    for (; i + 16 <= cnt; i += 16) {
        int u[8];
        #pragma unroll
        for (int j = 0; j < 8; j++) u[j] = __builtin_nontemporal_load(cp + i + 2 * j + half);
        uint2 t[8];
        #pragma unroll
        for (int j = 0; j < 8; j++) t[j] = xs4[(size_t)u[j] * 32 + hl];
        #pragma unroll
        for (int j = 0; j < 8; j++) {
            ax += bf16_lo(t[j].x); ay += bf16_hi(t[j].x);
            az += bf16_lo(t[j].y); aw += bf16_hi(t[j].y);
        }
    }
    if (i + 8 <= cnt) {
        int u[4];
        #pragma unroll
        for (int j = 0; j < 4; j++) u[j] = __builtin_nontemporal_load(cp + i + 2 * j + half);
        uint2 t[4];
        #pragma unroll
        for (int j = 0; j < 4; j++) t[j] = xs4[(size_t)u[j] * 32 + hl];
        #pragma unroll
        for (int j = 0; j < 4; j++) {
            ax += bf16_lo(t[j].x); ay += bf16_hi(t[j].x);
            az += bf16_lo(t[j].y); aw += bf16_hi(t[j].y);
        }
        i += 8;
    }
    if (i + 4 <= cnt) {
        int u[2];
        #pragma unroll
        for (int j = 0; j < 2; j++) u[j] = __builtin_nontemporal_load(cp + i + 2 * j + half);
        uint2 t[2];
        #pragma unroll
        for (int j = 0; j < 2; j++) t[j] = xs4[(size_t)u[j] * 32 + hl];
        #pragma unroll
        for (int j = 0; j < 2; j++) {
            ax += bf16_lo(t[j].x); ay += bf16_hi(t[j].x);
            az += bf16_lo(t[j].y); aw += bf16_hi(t[j].y);
        }
        i += 4;
    }
    if (i + 2 <= cnt) {
        int u = __builtin_nontemporal_load(cp + i + half);
        uint2 t = xs4[(size_t)u * 32 + hl];
        ax += bf16_lo(t.x); ay += bf16_hi(t.x);
        az += bf16_lo(t.y); aw += bf16_hi(t.y);
        i += 2;
    }
    if (i < cnt && half == 0) {
        int u = __builtin_nontemporal_load(cp + i);
        uint2 t = xs4[(size_t)u * 32 + hl];
        ax += bf16_lo(t.x); ay += bf16_hi(t.x);
        az += bf16_lo(t.y); aw += bf16_hi(t.y);
    }
    // combine the two halves (each edge was processed by exactly one half)
    ax += __shfl_xor(ax, 32, 64);
    ay += __shfl_xor(ay, 32, 64);
    az += __shfl_xor(az, 32, 64);
    aw += __shfl_xor(aw, 32, 64);
    // self-loop (added once post-combine; both halves compute, half 0 writes)
    uint2 s = xs4[(size_t)v * 32 + hl];
    ax += bf16_lo(s.x); ay += bf16_hi(s.x);
    az += bf16_lo(s.y); aw += bf16_hi(s.y);
    if (half == 0) {
        uint2 o;
        o.x = bf16_bits(ax * dv) | (bf16_bits(ay * dv) << 16);
        o.y = bf16_bits(az * dv) | (bf16_bits(aw * dv) << 16);
        agg4[(size_t)v * 32 + hl] = o;
    }
}

// ---------------------------------------------------------------------------
// 4. pack W1+W2 -> bf16 MFMA B-fragment order, nt-major: [nt][h][kt][lane][8]
// ---------------------------------------------------------------------------
__global__ void pack_w_kernel(const float* __restrict__ W1, const float* __restrict__ W2,
                              unsigned short* __restrict__ out) {
    int tid = blockIdx.x * blockDim.x + threadIdx.x;   // 2*KT*NT*64 = 6656
    if (tid >= 2 * KT_TILES * NT_TILES * 64) return;
    int lane = tid & 63;
    int nt = (tid >> 6) % NT_TILES;
    int kt = (tid / (64 * NT_TILES)) % KT_TILES;
    int h  = tid / (64 * NT_TILES * KT_TILES);
    const float* W = h ? W2 : W1;
    int q = lane >> 4, r = lane & 15;
    int nn = nt * 16 + r;
    size_t dst = ((size_t)((nt * 2 + h) * KT_TILES + kt)) * 512 + (size_t)lane * 8;
    for (int j = 0; j < 8; j++) {
        int k = kt * 32 + q * 8 + j;
        float val = (nn < OUT_C) ? W[(size_t)k * OUT_C + nn] : 0.f;
        out[dst + j] = (unsigned short)bf16_bits(val);
    }
}

// ---------------------------------------------------------------------------
// 5. fused 2-head MFMA GEMM with per-nt LDS staging of B (double-buffered,
//    register prefetch, one barrier per nt). Epilogue: biases hoisted; stores
//    issued row-major (13 adjacent 64B segments back-to-back -> line merges).
// ---------------------------------------------------------------------------
__global__ __launch_bounds__(256) void gemm_mfma_kernel(
        const unsigned short* __restrict__ agg,   // [M][128] bf16
        const unsigned short* __restrict__ Wpk,   // [NT][2][KT][64][8] bf16
        const float* __restrict__ b1, const float* __restrict__ b2,
        float* __restrict__ mu, float* __restrict__ ls, int M) {
    __shared__ uint4 Bs[2][512];                  // 2 x 8KB nt-slices
    int tid  = threadIdx.x;
    int wave = tid >> 6;
    int lane = tid & 63;
    int row0 = blockIdx.x * 64 + wave * 16;
    int q = lane >> 4, r = lane & 15;

    // A fragments: A[m = lane&15][k = q*8 + j], one per kt
    int arow = row0 + r; if (arow > M - 1) arow = M - 1;
    const unsigned short* ap = agg + (size_t)arow * IN_C + q * 8;
    bf16x8 afrag[KT_TILES];
    #pragma unroll
    for (int kt = 0; kt < KT_TILES; kt++) {
        uint4 u = *(const uint4*)(ap + kt * 32);
        afrag[kt] = __builtin_bit_cast(bf16x8, u);
    }

    f32x4 acc[2][NT_TILES];
    #pragma unroll
    for (int h = 0; h < 2; h++)
        #pragma unroll
        for (int nt = 0; nt < NT_TILES; nt++)
            acc[h][nt] = (f32x4){0.f, 0.f, 0.f, 0.f};

    const uint4* wsrc = (const uint4*)Wpk;
    uint4 pre0 = wsrc[tid];
    uint4 pre1 = wsrc[tid + 256];

    for (int nt = 0; nt < NT_TILES; nt++) {
        int buf = nt & 1;
        Bs[buf][tid]       = pre0;
        Bs[buf][tid + 256] = pre1;
        __syncthreads();
        if (nt + 1 < NT_TILES) {
            pre0 = wsrc[(nt + 1) * 512 + tid];
            pre1 = wsrc[(nt + 1) * 512 + tid + 256];
        }
        #pragma unroll
        for (int h = 0; h < 2; h++) {
            f32x4 c = acc[h][nt];
            #pragma unroll
            for (int kt = 0; kt < KT_TILES; kt++) {
                uint4 u = Bs[buf][(h * KT_TILES + kt) * 64 + lane];
                bf16x8 bfrag = __builtin_bit_cast(bf16x8, u);
                c = __builtin_amdgcn_mfma_f32_16x16x32_bf16(afrag[kt], bfrag, c, 0, 0, 0);
            }
            acc[h][nt] = c;
        }
        // buffer written next at nt+2; all waves passed the nt+1 barrier by then
    }

    // epilogue: C/D layout col = lane&15, row = q*4 + reg
    float bv1r[NT_TILES], bv2r[NT_TILES];
    #pragma unroll
    for (int nt = 0; nt < NT_TILES; nt++) {
        int colx = nt * 16 + r;
        bool cok = colx < OUT_C;
        bv1r[nt] = cok ? b1[colx] : 0.f;
        bv2r[nt] = cok ? b2[colx] : 0.f;
    }
    #pragma unroll
    for (int reg = 0; reg < 4; reg++) {
        int gr = row0 + q * 4 + reg;
        if (gr < M) {
            float* mrow = mu + (size_t)gr * OUT_C;
            #pragma unroll
            for (int nt = 0; nt < NT_TILES; nt++) {
                int colx = nt * 16 + r;
                if (colx < OUT_C) mrow[colx] = acc[0][nt][reg] + bv1r[nt];
            }
            float* lrow = ls + (size_t)gr * OUT_C;
            #pragma unroll
            for (int nt = 0; nt < NT_TILES; nt++) {
                int colx = nt * 16 + r;
                if (colx < OUT_C) lrow[colx] = acc[1][nt][reg] + bv2r[nt];
            }
        }
    }
}

// ---------------------------------------------------------------------------
extern "C" void kernel_launch(void* const* d_in, const int* in_sizes, int n_in,
                              void* d_out, int out_size, void* d_ws, size_t ws_size,
                              hipStream_t stream) {
    const float* x  = (const float*)d_in[0];
    const int*   ei = (const int*)d_in[1];
    const float* W1 = (const float*)d_in[2];
    const float* b1 = (const float*)d_in[3];
    const float* W2 = (const float*)d_in[4];
    const float* b2 = (const float*)d_in[5];

    const int n = in_sizes[0] / IN_C;      // 100000
    const int E = in_sizes[1] / 2;         // 1600000
    const int* row = ei;                   // src
    const int* col = ei + E;               // dst

    float* mu = (float*)d_out;
    float* ls = (float*)d_out + (size_t)n * OUT_C;

    // workspace layout (byte offsets, 16B aligned)
    char* ws = (char*)d_ws;
    int*            deg     = (int*)           (ws + 0);
    float*          dinv    = (float*)         (ws + 524288);
    int*            offsets = (int*)           (ws + 1048576);
    int*            gcount  = (int*)           (ws + 1572864);          // NB ints
    int*            csr_src = (int*)           (ws + 2162688);          // E ints
    unsigned int*   xs2     = (unsigned int*)  (ws + 8562688);          // n*64 uints
    unsigned int*   gbuf    = (unsigned int*)  (ws + 34162688);         // NB*BCAP uints
    unsigned int*   agg2    = (unsigned int*)  (ws + 42170368);         // n*64 uints
    unsigned short* Wpk     = (unsigned short*)(ws + 67770368);         // 2*3328*8 bf16

    (void)hipMemsetAsync(gcount, 0, NB * sizeof(int), stream);

    pack_w_kernel<<<(2 * KT_TILES * NT_TILES * 64 + 255) / 256, 256, 0, stream>>>(W1, W2, Wpk);

    partition_kernel<<<(E + PART_CH - 1) / PART_CH, 256, 0, stream>>>(row, col, E, gcount, gbuf);

    build_kernel<<<NB, 256, 0, stream>>>(gbuf, gcount, x, deg, offsets, dinv,
                                         csr_src, (uint2*)xs2, n);

    gather_kernel<<<(n + 3) / 4, 256, 0, stream>>>(
        (const uint2*)xs2, dinv, offsets, deg, csr_src, (uint2*)agg2, n);

    gemm_mfma_kernel<<<(n + 63) / 64, 256, 0, stream>>>(
        (const unsigned short*)agg2, Wpk, b1, b2, mu, ls, n);
}

// Round 9
// 360.879 us; speedup vs baseline: 1.0261x; 1.0101x over previous
//
#include <hip/hip_runtime.h>

#define N_NODES 100000
#define IN_C    128
#define OUT_C   200
#define NT_TILES 13            // ceil(200/16)
#define KT_TILES 4             // 128/32

// ---- bucket partition params ----------------------------------------------
#define PSHIFT  8
#define NPB     256                        // nodes per bucket = 1<<PSHIFT
#define NB      391                        // ceil(100000/256)
#define NB_POW2 512
#define BCAP    5120                       // per-bucket capacity (mean 4092, +16 sigma)
#define PART_CH 4096                       // edges per partition block (391 blocks)
#define SEQ_P   16                         // PART_CH/256 edges per thread
#define SEQ_B   20                         // ceil(BCAP/256) entries per thread

typedef __bf16 bf16_t;
typedef bf16_t bf16x8 __attribute__((ext_vector_type(8)));
typedef float  f32x4  __attribute__((ext_vector_type(4)));

// ---- bf16 bit helpers (RNE) -----------------------------------------------
__device__ __forceinline__ unsigned int bf16_bits(float f) {
    unsigned int u = __builtin_bit_cast(unsigned int, f);
    return (u + 0x7FFFu + ((u >> 16) & 1u)) >> 16;
}
__device__ __forceinline__ float bf16_lo(unsigned int p) {
    return __builtin_bit_cast(float, p << 16);
}
__device__ __forceinline__ float bf16_hi(unsigned int p) {
    return __builtin_bit_cast(float, p & 0xFFFF0000u);
}

// ---------------------------------------------------------------------------
// 1. partition edges into NB dst-buckets, LDS-staged so global writes are
//    coalesced runs. SINGLE edge pass (histogram atomicAdd returns seq).
// ---------------------------------------------------------------------------
__global__ __launch_bounds__(256) void partition_kernel(
        const int* __restrict__ row, const int* __restrict__ col, int E,
        int* __restrict__ gcount, unsigned int* __restrict__ gbuf) {
    __shared__ int hist[NB];
    __shared__ int base[NB];
    __shared__ int lofs[NB];
    __shared__ int pscan[256];
    __shared__ unsigned int stage[PART_CH];
    __shared__ unsigned short sb[PART_CH];
    const int tid = threadIdx.x;
    const int chunk = blockIdx.x * PART_CH;
    int cend = E - chunk; if (cend > PART_CH) cend = PART_CH;

    for (int i = tid; i < NB; i += 256) hist[i] = 0;
    __syncthreads();

    unsigned int   pay[SEQ_P];
    unsigned short eb[SEQ_P];
    unsigned short sq[SEQ_P];
    #pragma unroll
    for (int k = 0; k < SEQ_P; k++) {
        int i = tid + k * 256;
        eb[k] = 0xFFFFu;
        if (i < cend) {
            int c = __builtin_nontemporal_load(col + chunk + i);
            int r = __builtin_nontemporal_load(row + chunk + i);
            int b = (c >> PSHIFT) & (NB_POW2 - 1);
            if (b >= NB) b = NB - 1;
            pay[k] = (unsigned int)((c & (NPB - 1)) | (r << PSHIFT));
            eb[k]  = (unsigned short)b;
            sq[k]  = (unsigned short)atomicAdd(&hist[b], 1);
        }
    }
    __syncthreads();

    for (int i = tid; i < NB; i += 256)
        base[i] = atomicAdd(&gcount[i], hist[i]);

    // exclusive scan of hist -> lofs (pair-per-thread Hillis-Steele)
    int v0 = (2 * tid     < NB) ? hist[2 * tid]     : 0;
    int v1 = (2 * tid + 1 < NB) ? hist[2 * tid + 1] : 0;
    int s = v0 + v1;
    pscan[tid] = s;
    __syncthreads();
    for (int off = 1; off < 256; off <<= 1) {
        int u = (tid >= off) ? pscan[tid - off] : 0;
        __syncthreads();
        pscan[tid] += u;
        __syncthreads();
    }
    int ep = pscan[tid] - s;
    if (2 * tid     < NB) lofs[2 * tid]     = ep;
    if (2 * tid + 1 < NB) lofs[2 * tid + 1] = ep + v0;
    __syncthreads();

    #pragma unroll
    for (int k = 0; k < SEQ_P; k++) {
        if (eb[k] != 0xFFFFu) {
            int p = lofs[eb[k]] + sq[k];
            stage[p] = pay[k];
            sb[p] = eb[k];
        }
    }
    __syncthreads();

    for (int i = tid; i < cend; i += 256) {
        int b = sb[i];
        int p = base[b] + (i - lofs[b]);
        if (p < BCAP) gbuf[(size_t)b * BCAP + p] = stage[i];
    }
}

// ---------------------------------------------------------------------------
// 2. per-bucket CSR build + in-block bucket prefix + fused convert
//    (xs = dinv*x -> bf16x2). od[v] = (csr offset, degree) packed int2.
// ---------------------------------------------------------------------------
__global__ __launch_bounds__(256) void build_kernel(
        const unsigned int* __restrict__ gbuf, const int* __restrict__ gcount,
        const float* __restrict__ x,
        int2* __restrict__ od, float* __restrict__ dinv,
        int* __restrict__ csr_src, uint2* __restrict__ xs4, int n) {
    __shared__ int cnt[NPB];
    __shared__ int cur[NPB];
    __shared__ int pscan[256];
    __shared__ int gb[512];
    const int b = blockIdx.x;
    const int tid = threadIdx.x;

    // in-block exclusive prefix over clamped bucket counts
    int g0 = (2 * tid     < NB) ? gcount[2 * tid]     : 0;
    int g1 = (2 * tid + 1 < NB) ? gcount[2 * tid + 1] : 0;
    if (g0 > BCAP) g0 = BCAP;
    if (g1 > BCAP) g1 = BCAP;
    int gs = g0 + g1;
    pscan[tid] = gs;
    cnt[tid] = 0;
    __syncthreads();
    for (int off = 1; off < 256; off <<= 1) {
        int u = (tid >= off) ? pscan[tid - off] : 0;
        __syncthreads();
        pscan[tid] += u;
        __syncthreads();
    }
    int gep = pscan[tid] - gs;
    gb[2 * tid]     = gep;
    gb[2 * tid + 1] = gep + g0;
    __syncthreads();

    const int cbase = gb[b];
    int total = gcount[b]; if (total > BCAP) total = BCAP;
    const unsigned int* bp = gbuf + (size_t)b * BCAP;

    // single entry pass: count-atomic returns sequence number
    unsigned int   ee[SEQ_B];
    unsigned short sq[SEQ_B];
    #pragma unroll
    for (int k = 0; k < SEQ_B; k++) {
        int i = tid + k * 256;
        ee[k] = 0xFFFFFFFFu;
        if (i < total) {
            unsigned int e = __builtin_nontemporal_load(bp + i);
            ee[k] = e;
            sq[k] = (unsigned short)atomicAdd(&cnt[e & (NPB - 1)], 1);
        }
    }
    __syncthreads();

    // per-node exclusive scan -> od/dinv
    int c = cnt[tid];
    pscan[tid] = c;
    __syncthreads();
    for (int off = 1; off < 256; off <<= 1) {
        int u = (tid >= off) ? pscan[tid - off] : 0;
        __syncthreads();
        pscan[tid] += u;
        __syncthreads();
    }
    int excl = pscan[tid] - c;
    cur[tid] = excl;
    int v = b * NPB + tid;
    if (v < n) {
        od[v] = (int2){cbase + excl, c};
        dinv[v] = rsqrtf((float)(c + 1));   // +1 self-loop
    }
    __syncthreads();

    // CSR fill (block-local region -> full L2 lines)
    #pragma unroll
    for (int k = 0; k < SEQ_B; k++) {
        if (ee[k] != 0xFFFFFFFFu) {
            int p = cur[ee[k] & (NPB - 1)] + (int)sq[k];
            csr_src[cbase + p] = (int)(ee[k] >> PSHIFT);
        }
    }

    // fused convert: this bucket's 256 x-rows -> xs4 (coalesced)
    int wv = tid >> 6, ln = tid & 63;
    int hlf = ln >> 5, hl2 = ln & 31;
    for (int m = 0; m < 64; m += 2) {
        int local = wv * 64 + m + hlf;
        int nv = b * NPB + local;
        if (nv < n) {
            float dv = rsqrtf((float)(cnt[local] + 1));
            f32x4 f = __builtin_nontemporal_load((const f32x4*)x + (size_t)nv * 32 + hl2);
            uint2 o;
            o.x = bf16_bits(f.x * dv) | (bf16_bits(f.y * dv) << 16);
            o.y = bf16_bits(f.z * dv) | (bf16_bits(f.w * dv) << 16);
            xs4[(size_t)nv * 32 + hl2] = o;
        }
    }
}

// ---------------------------------------------------------------------------
// 3. gather: agg[v] = dv * ( xs[v] + sum_{u->v} xs[u] )
//    One wave per node, FOUR edges per step via uint4 (16B/lane, 16 lanes per
//    edge-group): same in-flight bytes as R5's uint2 ladder but HALF the load
//    instructions; idx loads are group-uniform (1 line per 4 groups).
// ---------------------------------------------------------------------------
__global__ __launch_bounds__(256) void gather_kernel(
        const uint4* __restrict__ xs16, const float* __restrict__ dinv,
        const int2* __restrict__ od,
        const int* __restrict__ csr_src, uint4* __restrict__ agg16, int n) {
    int wave = threadIdx.x >> 6;
    int lane = threadIdx.x & 63;
    int g = lane >> 4;             // edge slot within 4-edge step
    int w = lane & 15;             // channel-quad (8 channels = 16B)
    int v = blockIdx.x * 4 + wave;
    if (v >= n) return;
    float dv = dinv[v];
    int2 odv = od[v];
    int start = odv.x, cnt = odv.y;
    float a0 = 0.f, a1 = 0.f, a2 = 0.f, a3 = 0.f;
    float a4 = 0.f, a5 = 0.f, a6 = 0.f, a7 = 0.f;

    const int* cp = csr_src + start;
    int i = 0;
    for (; i + 16 <= cnt; i += 16) {
        int id4[4];
        #pragma unroll
        for (int j = 0; j < 4; j++)
            id4[j] = __builtin_nontemporal_load(cp + i + 4 * j + g);
        uint4 t[4];
        #pragma unroll
        for (int j = 0; j < 4; j++)
            t[j] = xs16[(size_t)id4[j] * 16 + w];
        #pragma unroll
        for (int j = 0; j < 4; j++) {
            a0 += bf16_lo(t[j].x); a1 += bf16_hi(t[j].x);
            a2 += bf16_lo(t[j].y); a3 += bf16_hi(t[j].y);
            a4 += bf16_lo(t[j].z); a5 += bf16_hi(t[j].z);
            a6 += bf16_lo(t[j].w); a7 += bf16_hi(t[j].w);
        }
    }
    for (; i + 4 <= cnt; i += 4) {
        int idx = __builtin_nontemporal_load(cp + i + g);
        uint4 t = xs16[(size_t)idx * 16 + w];
        a0 += bf16_lo(t.x); a1 += bf16_hi(t.x);
        a2 += bf16_lo(t.y); a3 += bf16_hi(t.y);
        a4 += bf16_lo(t.z); a5 += bf16_hi(t.z);
        a6 += bf16_lo(t.w); a7 += bf16_hi(t.w);
    }
    if (i < cnt) {
        int e = i + g;
        if (e < cnt) {
            int idx = __builtin_nontemporal_load(cp + e);
            uint4 t = xs16[(size_t)idx * 16 + w];
            a0 += bf16_lo(t.x); a1 += bf16_hi(t.x);
            a2 += bf16_lo(t.y); a3 += bf16_hi(t.y);
            a4 += bf16_lo(t.z); a5 += bf16_hi(t.z);
            a6 += bf16_lo(t.w); a7 += bf16_hi(t.w);
        }
    }
    // reduce across the 4 edge-groups (xor 16, then 32) — w is preserved
    a0 += __shfl_xor(a0, 16, 64); a0 += __shfl_xor(a0, 32, 64);
    a1 += __shfl_xor(a1, 16, 64); a1 += __shfl_xor(a1, 32, 64);
    a2 += __shfl_xor(a2, 16, 64); a2 += __shfl_xor(a2, 32, 64);
    a3 += __shfl_xor(a3, 16, 64); a3 += __shfl_xor(a3, 32, 64);
    a4 += __shfl_xor(a4, 16, 64); a4 += __shfl_xor(a4, 32, 64);
    a5 += __shfl_xor(a5, 16, 64); a5 += __shfl_xor(a5, 32, 64);
    a6 += __shfl_xor(a6, 16, 64); a6 += __shfl_xor(a6, 32, 64);
    a7 += __shfl_xor(a7, 16, 64); a7 += __shfl_xor(a7, 32, 64);
    // self-loop
    uint4 s = xs16[(size_t)v * 16 + w];
    a0 += bf16_lo(s.x); a1 += bf16_hi(s.x);
    a2 += bf16_lo(s.y); a3 += bf16_hi(s.y);
    a4 += bf16_lo(s.z); a5 += bf16_hi(s.z);
    a6 += bf16_lo(s.w); a7 += bf16_hi(s.w);
    if (g == 0) {
        uint4 o;
        o.x = bf16_bits(a0 * dv) | (bf16_bits(a1 * dv) << 16);
        o.y = bf16_bits(a2 * dv) | (bf16_bits(a3 * dv) << 16);
        o.z = bf16_bits(a4 * dv) | (bf16_bits(a5 * dv) << 16);
        o.w = bf16_bits(a6 * dv) | (bf16_bits(a7 * dv) << 16);
        agg16[(size_t)v * 16 + w] = o;
    }
}

// ---------------------------------------------------------------------------
// 4. pack W1+W2 -> bf16 MFMA B-fragment order (also clears gcount: kills the
//    separate memset launch; same-stream ordering guarantees visibility).
// ---------------------------------------------------------------------------
__global__ void pack_w_kernel(const float* __restrict__ W1, const float* __restrict__ W2,
                              unsigned short* __restrict__ out, int* __restrict__ gcount) {
    int tid = blockIdx.x * blockDim.x + threadIdx.x;   // 2*KT*NT*64 = 6656
    if (tid < NB) gcount[tid] = 0;
    if (tid >= 2 * KT_TILES * NT_TILES * 64) return;
    int lane = tid & 63;
    int nt = (tid >> 6) % NT_TILES;
    int kt = (tid / (64 * NT_TILES)) % KT_TILES;
    int h  = tid / (64 * NT_TILES * KT_TILES);
    const float* W = h ? W2 : W1;
    int q = lane >> 4, r = lane & 15;
    int nn = nt * 16 + r;
    size_t dst = ((size_t)((nt * 2 + h) * KT_TILES + kt)) * 512 + (size_t)lane * 8;
    for (int j = 0; j < 8; j++) {
        int k = kt * 32 + q * 8 + j;
        float val = (nn < OUT_C) ? W[(size_t)k * OUT_C + nn] : 0.f;
        out[dst + j] = (unsigned short)bf16_bits(val);
    }
}

// ---------------------------------------------------------------------------
// 5. fused 2-head MFMA GEMM with per-nt LDS staging of B (double-buffered,
//    register prefetch, one barrier per nt). Plain stores (R5/R8 measured best).
// ---------------------------------------------------------------------------
__global__ __launch_bounds__(256) void gemm_mfma_kernel(
        const unsigned short* __restrict__ agg,   // [M][128] bf16
        const unsigned short* __restrict__ Wpk,   // [NT][2][KT][64][8] bf16
        const float* __restrict__ b1, const float* __restrict__ b2,
        float* __restrict__ mu, float* __restrict__ ls, int M) {
    __shared__ uint4 Bs[2][512];                  // 2 x 8KB nt-slices
    int tid  = threadIdx.x;
    int wave = tid >> 6;
    int lane = tid & 63;
    int row0 = blockIdx.x * 64 + wave * 16;
    int q = lane >> 4, r = lane & 15;

    int arow = row0 + r; if (arow > M - 1) arow = M - 1;
    const unsigned short* ap = agg + (size_t)arow * IN_C + q * 8;
    bf16x8 afrag[KT_TILES];
    #pragma unroll
    for (int kt = 0; kt < KT_TILES; kt++) {
        uint4 u = *(const uint4*)(ap + kt * 32);
        afrag[kt] = __builtin_bit_cast(bf16x8, u);
    }

    f32x4 acc[2][NT_TILES];
    #pragma unroll
    for (int h = 0; h < 2; h++)
        #pragma unroll
        for (int nt = 0; nt < NT_TILES; nt++)
            acc[h][nt] = (f32x4){0.f, 0.f, 0.f, 0.f};

    const uint4* wsrc = (const uint4*)Wpk;
    uint4 pre0 = wsrc[tid];
    uint4 pre1 = wsrc[tid + 256];

    for (int nt = 0; nt < NT_TILES; nt++) {
        int buf = nt & 1;
        Bs[buf][tid]       = pre0;
        Bs[buf][tid + 256] = pre1;
        __syncthreads();
        if (nt + 1 < NT_TILES) {
            pre0 = wsrc[(nt + 1) * 512 + tid];
            pre1 = wsrc[(nt + 1) * 512 + tid + 256];
        }
        #pragma unroll
        for (int h = 0; h < 2; h++) {
            f32x4 c = acc[h][nt];
            #pragma unroll
            for (int kt = 0; kt < KT_TILES; kt++) {
                uint4 u = Bs[buf][(h * KT_TILES + kt) * 64 + lane];
                bf16x8 bfrag = __builtin_bit_cast(bf16x8, u);
                c = __builtin_amdgcn_mfma_f32_16x16x32_bf16(afrag[kt], bfrag, c, 0, 0, 0);
            }
            acc[h][nt] = c;
        }
    }

    // epilogue: C/D layout col = lane&15, row = q*4 + reg
    float bv1r[NT_TILES], bv2r[NT_TILES];
    #pragma unroll
    for (int nt = 0; nt < NT_TILES; nt++) {
        int colx = nt * 16 + r;
        bool cok = colx < OUT_C;
        bv1r[nt] = cok ? b1[colx] : 0.f;
        bv2r[nt] = cok ? b2[colx] : 0.f;
    }
    #pragma unroll
    for (int reg = 0; reg < 4; reg++) {
        int gr = row0 + q * 4 + reg;
        if (gr < M) {
            float* mrow = mu + (size_t)gr * OUT_C;
            #pragma unroll
            for (int nt = 0; nt < NT_TILES; nt++) {
                int colx = nt * 16 + r;
                if (colx < OUT_C) mrow[colx] = acc[0][nt][reg] + bv1r[nt];
            }
            float* lrow = ls + (size_t)gr * OUT_C;
            #pragma unroll
            for (int nt = 0; nt < NT_TILES; nt++) {
                int colx = nt * 16 + r;
                if (colx < OUT_C) lrow[colx] = acc[1][nt][reg] + bv2r[nt];
            }
        }
    }
}

// ---------------------------------------------------------------------------
extern "C" void kernel_launch(void* const* d_in, const int* in_sizes, int n_in,
                              void* d_out, int out_size, void* d_ws, size_t ws_size,
                              hipStream_t stream) {
    const float* x  = (const float*)d_in[0];
    const int*   ei = (const int*)d_in[1];
    const float* W1 = (const float*)d_in[2];
    const float* b1 = (const float*)d_in[3];
    const float* W2 = (const float*)d_in[4];
    const float* b2 = (const float*)d_in[5];

    const int n = in_sizes[0] / IN_C;      // 100000
    const int E = in_sizes[1] / 2;         // 1600000
    const int* row = ei;                   // src
    const int* col = ei + E;               // dst

    float* mu = (float*)d_out;
    float* ls = (float*)d_out + (size_t)n * OUT_C;

    // workspace layout (byte offsets, 16B aligned)
    char* ws = (char*)d_ws;
    int2*           od      = (int2*)          (ws + 0);                // n int2
    float*          dinv    = (float*)         (ws + 1048576);          // n floats
    int*            gcount  = (int*)           (ws + 1572864);          // NB ints
    int*            csr_src = (int*)           (ws + 2162688);          // E ints
    unsigned int*   xs2     = (unsigned int*)  (ws + 8562688);          // n*64 uints
    unsigned int*   gbuf    = (unsigned int*)  (ws + 34162688);         // NB*BCAP uints
    unsigned int*   agg2    = (unsigned int*)  (ws + 42170368);         // n*64 uints
    unsigned short* Wpk     = (unsigned short*)(ws + 67770368);         // 2*3328*8 bf16

    pack_w_kernel<<<(2 * KT_TILES * NT_TILES * 64 + 255) / 256, 256, 0, stream>>>(
        W1, W2, Wpk, gcount);

    partition_kernel<<<(E + PART_CH - 1) / PART_CH, 256, 0, stream>>>(row, col, E, gcount, gbuf);

    build_kernel<<<NB, 256, 0, stream>>>(gbuf, gcount, x, od, dinv,
                                         csr_src, (uint2*)xs2, n);

    gather_kernel<<<(n + 3) / 4, 256, 0, stream>>>(
        (const uint4*)xs2, dinv, od, csr_src, (uint4*)agg2, n);

    gemm_mfma_kernel<<<(n + 63) / 64, 256, 0, stream>>>(
        (const unsigned short*)agg2, Wpk, b1, b2, mu, ls, n);
}